// Round 5
// baseline (938.281 us; speedup 1.0000x reference)
//
#include <hip/hip_runtime.h>
#include <hip/hip_bf16.h>
#include <math.h>

// Model: 5x (conv1d + bias + LeakyReLU(0.1) + BatchNorm(train-stats)) on
// embedded context, then content attention over a 4096-slot memory, concat
// [emb(x), cfeat, m_out] -> fc -> softmax over 32000 vocab.
//
// R3: convs as strided-view bf16 MFMA GEMMs, BN folded into next conv's
//     weights, split-K for conv5/m_out, LDS data-quad rotation, online
//     softmax_fc.
// R4: fc GEMM on 256x256/BK=64 8-wave dbuf kernel (counted vmcnt, raw
//     s_barrier). Landed at MfmaUtil 24.6% -- coarse phase-split (pure-read
//     phase + pure-MFMA phases) = m196 anti-pattern.
// R5: faithful per-phase interleave: 4 phases/K-tile, each
//     {stage(P0) | ds_read quadrant ops | bar | lgkmcnt(0) | setprio |
//      16 MFMA | setprio | bar}; residency gate = vmcnt(0) at P3-end where
//     all outstanding loads are ~3 phases old (near-free, not a fresh drain).

#define N_SAMP 1024

typedef __bf16 bf16x8 __attribute__((ext_vector_type(8)));
typedef __bf16 bf16x4 __attribute__((ext_vector_type(4)));
typedef float  f32x4  __attribute__((ext_vector_type(4)));

// ---------------------------------------------------------------- reductions
__device__ __forceinline__ float blockReduceMax256(float v) {
    __shared__ float sm[4];
    #pragma unroll
    for (int off = 32; off > 0; off >>= 1) v = fmaxf(v, __shfl_down(v, off, 64));
    if ((threadIdx.x & 63) == 0) sm[threadIdx.x >> 6] = v;
    __syncthreads();
    v = fmaxf(fmaxf(sm[0], sm[1]), fmaxf(sm[2], sm[3]));
    __syncthreads();
    return v;
}

__device__ __forceinline__ float blockReduceSum256(float v) {
    __shared__ float sm[4];
    #pragma unroll
    for (int off = 32; off > 0; off >>= 1) v += __shfl_down(v, off, 64);
    if ((threadIdx.x & 63) == 0) sm[threadIdx.x >> 6] = v;
    __syncthreads();
    v = sm[0] + sm[1] + sm[2] + sm[3];
    __syncthreads();
    return v;
}

// ------------------------------------------------------- conv1 input prep
__global__ __launch_bounds__(256)
void gather_tr_kernel(const int* __restrict__ Cidx, const float* __restrict__ Emb,
                      __bf16* __restrict__ Gt) {
    const int n = blockIdx.x;
    __shared__ int idx[64];
    __shared__ float t[64][65];
    if (threadIdx.x < 64) idx[threadIdx.x] = Cidx[n * 64 + threadIdx.x];
    __bf16* g = Gt + (size_t)n * (262 * 64);
    for (int i = threadIdx.x; i < 6 * 64; i += 256) {
        int r = i >> 6;
        int phys = (r < 2) ? r : r + 256;   // 0,1,258,259,260,261
        g[(size_t)phys * 64 + (i & 63)] = (__bf16)0.f;
    }
    for (int c0 = 0; c0 < 256; c0 += 64) {
        __syncthreads();
        for (int i = threadIdx.x; i < 4096; i += 256) {
            int ci = i >> 6, li = i & 63;
            t[ci][li] = Emb[(size_t)idx[ci] * 256 + c0 + li];
        }
        __syncthreads();
        for (int i = threadIdx.x; i < 4096; i += 256) {
            int li = i >> 6, ci = i & 63;
            g[(size_t)(2 + c0 + li) * 64 + ci] = (__bf16)t[ci][li];
        }
    }
}

// ------------------------------------------------- weight transform + BN fold
__global__ __launch_bounds__(256)
void wt_fold_kernel(const float* __restrict__ W, const float* __restrict__ B,
                    const float* __restrict__ SS, __bf16* __restrict__ Wt,
                    float* __restrict__ bias, int CO, int CI, int KW) {
    const int co = blockIdx.x;
    const int K = CI * KW;
    float local = 0.f;
    if (co < CO) {
        for (int i = threadIdx.x; i < K; i += 256) {
            int k = i / CI, ci = i - k * CI;
            float w = W[((size_t)co * CI + ci) * KW + k];
            float sc = SS ? SS[ci] : 1.f;
            Wt[(size_t)co * K + i] = (__bf16)(w * sc);
            if (SS) local = fmaf(SS[CI + ci], w, local);
        }
    } else {
        for (int i = threadIdx.x; i < K; i += 256)
            Wt[(size_t)co * K + i] = (__bf16)0.f;
    }
    __shared__ float sm[4];
    #pragma unroll
    for (int off = 32; off > 0; off >>= 1) local += __shfl_down(local, off, 64);
    if ((threadIdx.x & 63) == 0) sm[threadIdx.x >> 6] = local;
    __syncthreads();
    if (threadIdx.x == 0 && co < CO)
        bias[co] = B[co] + sm[0] + sm[1] + sm[2] + sm[3];
}

// ------------------------------------------------- pad-row fill (post-stats)
__global__ __launch_bounds__(256)
void padfill_kernel(__bf16* __restrict__ Y, const float* __restrict__ SS,
                    int C, int LSTR, int4 rows, int nrows) {
    const int n = blockIdx.x;
    const int rr[4] = {rows.x, rows.y, rows.z, rows.w};
    for (int i = threadIdx.x; i < nrows * C; i += 256) {
        int j = i / C, c = i - j * C;
        float p = -SS[C + c] / SS[c];
        Y[((size_t)n * LSTR + rr[j]) * C + c] = (__bf16)p;
    }
}

// ---------------------------------------------------------------- batchnorm
template<int C, int LOUT, int LSTR, int NB>
__global__ __launch_bounds__(256)
void bn_stats_bf_kernel(const __bf16* __restrict__ Y, float2* __restrict__ partial) {
    constexpr int RPT = 256 / C;
    constexpr int M = N_SAMP * LOUT;
    const int col = threadIdx.x & (C - 1);
    const int rofs = threadIdx.x / C;
    float s = 0.f, s2 = 0.f;
    for (int m = blockIdx.x * RPT + rofs; m < M; m += NB * RPT) {
        int n = m / LOUT, l = m - n * LOUT;
        float v = (float)Y[((size_t)n * LSTR + 2 + l) * C + col];
        s += v; s2 = fmaf(v, v, s2);
    }
    __shared__ float sm[256], sm2[256];
    sm[threadIdx.x] = s; sm2[threadIdx.x] = s2;
    __syncthreads();
    #pragma unroll
    for (int off = 128; off >= C; off >>= 1) {
        if (threadIdx.x < off) {
            sm[threadIdx.x] += sm[threadIdx.x + off];
            sm2[threadIdx.x] += sm2[threadIdx.x + off];
        }
        __syncthreads();
    }
    if (threadIdx.x < C)
        partial[(size_t)blockIdx.x * C + threadIdx.x] =
            make_float2(sm[threadIdx.x], sm2[threadIdx.x]);
}

__global__ __launch_bounds__(256)
void bn_stats_cf_kernel(const float* __restrict__ Y, float2* __restrict__ partial) {
    const int n0 = blockIdx.x * 4;
    for (int c = threadIdx.x; c < 512; c += 256) {
        float s = 0.f, s2 = 0.f;
        #pragma unroll
        for (int r = 0; r < 4; r++) {
            float v = Y[(size_t)(n0 + r) * 512 + c];
            s += v; s2 = fmaf(v, v, s2);
        }
        partial[(size_t)blockIdx.x * 512 + c] = make_float2(s, s2);
    }
}

__global__ __launch_bounds__(64)
void bn_finalize_kernel(const float2* __restrict__ partial,
                        const float* __restrict__ G, const float* __restrict__ Be,
                        float* __restrict__ SS, int C, int NB, float invCnt) {
    const int c = blockIdx.x;
    float s = 0.f, s2 = 0.f;
    for (int i = threadIdx.x; i < NB; i += 64) {
        float2 p = partial[(size_t)i * C + c];
        s += p.x; s2 += p.y;
    }
    #pragma unroll
    for (int off = 32; off > 0; off >>= 1) {
        s  += __shfl_down(s,  off, 64);
        s2 += __shfl_down(s2, off, 64);
    }
    if (threadIdx.x == 0) {
        double mu  = (double)s * invCnt;
        double var = (double)s2 * invCnt - mu * mu;
        float sc = (float)((double)G[c] / sqrt(var + 1e-5));
        SS[c] = sc;
        SS[C + c] = (float)((double)Be[c] - mu * sc);
    }
}

// ---------------------------------------------------------------- MFMA GEMM
__device__ __forceinline__ void gld16(const __bf16* g, __bf16* l) {
    __builtin_amdgcn_global_load_lds(
        (const __attribute__((address_space(1))) unsigned int*)g,
        (__attribute__((address_space(3))) unsigned int*)l, 16, 0, 0);
}

// 128x128 / BK=32 general kernel (strided-view A, split-K, masked cols)
__global__ __launch_bounds__(256)
void mfma_gemm_bt(const __bf16* __restrict__ A, const __bf16* __restrict__ B,
                  const float* __restrict__ bias, void* __restrict__ Cv,
                  int N, int K, int ksplit,
                  int lda, int lda2, int rpbl, long long ablk,
                  int ldc2, long long csplit,
                  float scale, int leaky, int swz, int cdt) {
    __shared__ __bf16 As[128 * 32];
    __shared__ __bf16 Bs[128 * 32];
    const int tid = threadIdx.x;
    int bx = blockIdx.x, by = blockIdx.y;
    if (swz) {
        const int gx = gridDim.x;
        const int G = gx * gridDim.y;
        const int bid = by * gx + bx;
        const int fid = (bid & 7) * (G >> 3) + (bid >> 3);
        bx = fid % gx; by = fid / gx;
    }
    const int col0 = by * 128;
    const int rpbm = (1 << rpbl) - 1;

    const int r  = tid >> 2;
    const int kb = (((tid & 3) ^ ((tid >> 3) & 3))) * 8;
    const int r1 = r + 64;
    const __bf16* Ab = A + (size_t)bx * ablk;
    const __bf16* Ag0 = Ab + (size_t)(r  >> rpbl) * lda2 + (size_t)(r  & rpbm) * lda + kb;
    const __bf16* Ag1 = Ab + (size_t)(r1 >> rpbl) * lda2 + (size_t)(r1 & rpbm) * lda + kb;
    const __bf16* Bg0 = B + (size_t)(col0 + r ) * K + kb;
    const __bf16* Bg1 = B + (size_t)(col0 + r1) * K + kb;
    __bf16* Al0 = As + tid * 8;
    __bf16* Al1 = As + 2048 + tid * 8;
    __bf16* Bl0 = Bs + tid * 8;
    __bf16* Bl1 = Bs + 2048 + tid * 8;

    const int lane = tid & 63;
    const int wave = tid >> 6;
    const int wy = wave >> 1, wx = wave & 1;
    const int l15 = lane & 15, quad = lane >> 4;
    const int xq = (quad ^ ((l15 >> 1) & 3)) * 8;

    f32x4 acc[4][4] = {};

    const int k0s = blockIdx.z * ksplit;
    const int k0e = k0s + ksplit;
    for (int k0 = k0s; k0 < k0e; k0 += 32) {
        __syncthreads();
        gld16(Ag0 + k0, Al0);
        gld16(Ag1 + k0, Al1);
        gld16(Bg0 + k0, Bl0);
        gld16(Bg1 + k0, Bl1);
        __syncthreads();

        bf16x8 af[4], bfr[4];
        #pragma unroll
        for (int mi = 0; mi < 4; mi++)
            af[mi] = *(const bf16x8*)&As[(wy * 64 + mi * 16 + l15) * 32 + xq];
        #pragma unroll
        for (int ni = 0; ni < 4; ni++)
            bfr[ni] = *(const bf16x8*)&Bs[(wx * 64 + ni * 16 + l15) * 32 + xq];
        #pragma unroll
        for (int mi = 0; mi < 4; mi++)
            #pragma unroll
            for (int ni = 0; ni < 4; ni++)
                acc[mi][ni] = __builtin_amdgcn_mfma_f32_16x16x32_bf16(
                    af[mi], bfr[ni], acc[mi][ni], 0, 0, 0);
    }

    const long long cb = (long long)blockIdx.z * csplit
                       + (long long)bx * (long long)((128 >> rpbl) * ldc2);
    #pragma unroll
    for (int mi = 0; mi < 4; mi++) {
        #pragma unroll
        for (int ni = 0; ni < 4; ni++) {
            const int col = col0 + wx * 64 + ni * 16 + l15;
            if (col < N) {
                const float bv = bias ? bias[col] : 0.f;
                #pragma unroll
                for (int rg = 0; rg < 4; rg++) {
                    const int row = wy * 64 + mi * 16 + quad * 4 + rg;
                    const long long a = cb + (long long)(row >> rpbl) * ldc2
                                      + (long long)(row & rpbm) * N + col;
                    float t = acc[mi][ni][rg] * scale + bv;
                    if (leaky) t = t > 0.f ? t : 0.1f * t;
                    if (cdt) ((__bf16*)Cv)[a] = (__bf16)t;
                    else     ((float*)Cv)[a] = t;
                }
            }
        }
    }
}

// ---------------- 256x256 / BK=64 / 8-wave deep-pipelined GEMM -------------
// Requires M%256==0, N%256==0, K%64==0, K>=128. C = A·B^T + bias (fp32 out).
#define SBAR() do { __builtin_amdgcn_sched_barrier(0); \
                    __builtin_amdgcn_s_barrier(); \
                    __builtin_amdgcn_sched_barrier(0); } while (0)

#define WAIT_LGKM() do { asm volatile("s_waitcnt lgkmcnt(0)" ::: "memory"); \
                         __builtin_amdgcn_sched_barrier(0); } while (0)

#define LDA256(mb) do { \
    _Pragma("unroll") \
    for (int m_ = 0; m_ < 4; m_++) \
        _Pragma("unroll") \
        for (int k_ = 0; k_ < 2; k_++) \
            afr[mb][m_][k_] = *(const bf16x8*)&Asl[((mb) * 64 + m_ * 16) * 64 + \
                ((((k_) << 2) + quad) ^ rotA) * 8]; \
} while (0)

#define LDB256(nb) do { \
    _Pragma("unroll") \
    for (int n_ = 0; n_ < 2; n_++) \
        _Pragma("unroll") \
        for (int k_ = 0; k_ < 2; k_++) \
            bfr[nb][n_][k_] = *(const bf16x8*)&Bsl[((nb) * 32 + n_ * 16) * 64 + \
                ((((k_) << 2) + quad) ^ rotB) * 8]; \
} while (0)

#define MM256(mb, nb) do { \
    _Pragma("unroll") \
    for (int m_ = 0; m_ < 4; m_++) \
        _Pragma("unroll") \
        for (int n_ = 0; n_ < 2; n_++) \
            _Pragma("unroll") \
            for (int k_ = 0; k_ < 2; k_++) \
                acc[(mb) * 4 + m_][(nb) * 2 + n_] = \
                    __builtin_amdgcn_mfma_f32_16x16x32_bf16( \
                        afr[mb][m_][k_], bfr[nb][n_][k_], \
                        acc[(mb) * 4 + m_][(nb) * 2 + n_], 0, 0, 0); \
} while (0)

#define STG256(ko, bb) do { \
    const size_t ko_ = (size_t)(ko); \
    gld16(Ab + ko_,            AldsB + (bb) * 16384); \
    gld16(Ab + ko_ +     giK,  AldsB + (bb) * 16384 + 4096); \
    gld16(Ab + ko_ + 2 * giK,  AldsB + (bb) * 16384 + 8192); \
    gld16(Ab + ko_ + 3 * giK,  AldsB + (bb) * 16384 + 12288); \
    gld16(Bb + ko_,            BldsB + (bb) * 16384); \
    gld16(Bb + ko_ +     giK,  BldsB + (bb) * 16384 + 4096); \
    gld16(Bb + ko_ + 2 * giK,  BldsB + (bb) * 16384 + 8192); \
    gld16(Bb + ko_ + 3 * giK,  BldsB + (bb) * 16384 + 12288); \
} while (0)

__global__ __launch_bounds__(512, 2)
void mfma_gemm256_bt(const __bf16* __restrict__ A, const __bf16* __restrict__ B,
                     const float* __restrict__ bias, float* __restrict__ C,
                     int M, int N, int K, int nwg) {
    __shared__ __bf16 As2[2 * 16384];
    __shared__ __bf16 Bs2[2 * 16384];
    const int tid = threadIdx.x;

    // bijective XCD-chunked remap (m204)
    const int bid = blockIdx.x;
    const int q8 = nwg >> 3, r8 = nwg & 7;
    const int xcd = bid & 7, o8 = bid >> 3;
    const int fid = (xcd < r8 ? xcd * (q8 + 1) : r8 * (q8 + 1) + (xcd - r8) * q8) + o8;
    const int gx = M >> 8;
    const int bx = fid % gx, by = fid / gx;
    const int row0 = bx << 8, col0 = by << 8;

    const int lane = tid & 63;
    const int wave = tid >> 6;
    const int wr = wave >> 2, wc = wave & 3;   // 2 (M) x 4 (N)
    const int l15 = lane & 15, quad = lane >> 4;

    // staging: thread -> (row = i*64 + tid>>3, slot = tid&7); LDS[row][s]
    // holds global k-quad s ^ (row&7)  (3-bit data rotation)
    const int rloc = tid >> 3;
    const int sq   = tid & 7;
    const int ksel = (sq ^ (rloc & 7)) << 3;
    const __bf16* Ab = A + (size_t)(row0 + rloc) * K + ksel;
    const __bf16* Bb = B + (size_t)(col0 + rloc) * K + ksel;
    __bf16* AldsB = As2 + tid * 8;
    __bf16* BldsB = Bs2 + tid * 8;
    const size_t giK = (size_t)64 * K;

    const int arow = wr * 128 + l15;
    const int brow = wc * 64 + l15;
    const int rotA = arow & 7, rotB = brow & 7;

    f32x4 acc[8][4] = {};
    bf16x8 afr[2][4][2];   // [mi-bank][m][kk]
    bf16x8 bfr[2][2][2];   // [ni-bank][n][kk]

    const int NT = K >> 6;
    STG256(0, 0);
    asm volatile("s_waitcnt vmcnt(0)" ::: "memory");
    SBAR();                                   // tile 0 resident

    for (int t = 0; t < NT; ++t) {
        const int cb = t & 1;
        const __bf16* Asl = As2 + cb * 16384 + arow * 64;
        const __bf16* Bsl = Bs2 + cb * 16384 + brow * 64;

        // ---- P0: stage(t+1) | read af0,bf0 | MM(0,0) ----
        if (t + 1 < NT) STG256((size_t)(t + 1) * 64, cb ^ 1);
        LDA256(0);
        LDB256(0);
        SBAR();
        WAIT_LGKM();
        __builtin_amdgcn_s_setprio(1);
        MM256(0, 0);
        __builtin_amdgcn_s_setprio(0);
        SBAR();
        // ---- P1: read bf1 | MM(0,1) ----
        LDB256(1);
        SBAR();
        WAIT_LGKM();
        __builtin_amdgcn_s_setprio(1);
        MM256(0, 1);
        __builtin_amdgcn_s_setprio(0);
        SBAR();
        // ---- P2: read af1 | MM(1,0) ----
        LDA256(1);
        SBAR();
        WAIT_LGKM();
        __builtin_amdgcn_s_setprio(1);
        MM256(1, 0);
        __builtin_amdgcn_s_setprio(0);
        SBAR();
        // ---- P3: MM(1,1) | gate next tile (loads ~3 phases old) ----
        __builtin_amdgcn_s_setprio(1);
        MM256(1, 1);
        __builtin_amdgcn_s_setprio(0);
        asm volatile("s_waitcnt vmcnt(0)" ::: "memory");
        SBAR();                               // ends reads of buf[cb]; t+1 resident
    }

    #pragma unroll
    for (int mi = 0; mi < 8; mi++) {
        #pragma unroll
        for (int ni = 0; ni < 4; ni++) {
            const int colv = col0 + wc * 64 + ni * 16 + l15;
            const float bv = bias ? bias[colv] : 0.f;
            #pragma unroll
            for (int rg = 0; rg < 4; rg++) {
                const int row = row0 + wr * 128 + mi * 16 + quad * 4 + rg;
                C[(size_t)row * N + colv] = acc[mi][ni][rg] + bv;
            }
        }
    }
}

// ---------------------------------------------------------------- split-K
__global__ __launch_bounds__(256)
void splitk_reduce_kernel(const float* __restrict__ P, float* __restrict__ out,
                          const float* __restrict__ bias, int S, int MN, int N,
                          int leaky) {
    int i = blockIdx.x * 256 + threadIdx.x;
    const int tot = MN >> 2;
    if (i >= tot) return;
    float ax = 0.f, ay = 0.f, az = 0.f, aw = 0.f;
    for (int s = 0; s < S; s++) {
        float4 p = ((const float4*)(P + (size_t)s * MN))[i];
        ax += p.x; ay += p.y; az += p.z; aw += p.w;
    }
    const int c0 = (i * 4) & (N - 1);
    float4 o;
    o.x = ax + (bias ? bias[c0 + 0] : 0.f);
    o.y = ay + (bias ? bias[c0 + 1] : 0.f);
    o.z = az + (bias ? bias[c0 + 2] : 0.f);
    o.w = aw + (bias ? bias[c0 + 3] : 0.f);
    if (leaky) {
        o.x = o.x > 0.f ? o.x : 0.1f * o.x;
        o.y = o.y > 0.f ? o.y : 0.1f * o.y;
        o.z = o.z > 0.f ? o.z : 0.1f * o.z;
        o.w = o.w > 0.f ? o.w : 0.1f * o.w;
    }
    ((float4*)out)[i] = o;
}

// ---------------------------------------------------------------- casts
__global__ __launch_bounds__(256)
void cast_bf16_kernel(const float* __restrict__ in, __bf16* __restrict__ out, int n8) {
    int i = blockIdx.x * 256 + threadIdx.x;
    if (i >= n8) return;
    float4 a = ((const float4*)in)[2 * i];
    float4 b = ((const float4*)in)[2 * i + 1];
    bf16x8 v;
    v[0] = (__bf16)a.x; v[1] = (__bf16)a.y; v[2] = (__bf16)a.z; v[3] = (__bf16)a.w;
    v[4] = (__bf16)b.x; v[5] = (__bf16)b.y; v[6] = (__bf16)b.z; v[7] = (__bf16)b.w;
    ((bf16x8*)out)[i] = v;
}

__global__ __launch_bounds__(256)
void bn_apply_both_kernel(float* __restrict__ Y, __bf16* __restrict__ Yb,
                          const float* __restrict__ SS, int n4) {
    int i = blockIdx.x * 256 + threadIdx.x;
    if (i >= n4) return;
    float4 v = ((float4*)Y)[i];
    const int c = (i * 4) & 511;
    v.x = fmaf(v.x, SS[c + 0], SS[512 + c + 0]);
    v.y = fmaf(v.y, SS[c + 1], SS[512 + c + 1]);
    v.z = fmaf(v.z, SS[c + 2], SS[512 + c + 2]);
    v.w = fmaf(v.w, SS[c + 3], SS[512 + c + 3]);
    ((float4*)Y)[i] = v;
    bf16x4 o;
    o[0] = (__bf16)v.x; o[1] = (__bf16)v.y; o[2] = (__bf16)v.z; o[3] = (__bf16)v.w;
    ((bf16x4*)Yb)[i] = o;
}

__global__ __launch_bounds__(256)
void transpose_cast_kernel(const float* __restrict__ in, __bf16* __restrict__ out,
                           int R, int C) {
    __shared__ float t[32][33];
    const int c0 = blockIdx.x * 32, r0 = blockIdx.y * 32;
    const int cc = threadIdx.x & 31, rr = threadIdx.x >> 5;   // rr 0..7
    #pragma unroll
    for (int i = 0; i < 32; i += 8)
        t[rr + i][cc] = in[(size_t)(r0 + rr + i) * C + c0 + cc];
    __syncthreads();
    #pragma unroll
    for (int i = 0; i < 32; i += 8)
        out[(size_t)(c0 + rr + i) * R + r0 + cc] = (__bf16)t[cc][rr + i];
}

// ---------------------------------------------------------------- softmaxes
__global__ __launch_bounds__(256)
void softmax4k_kernel(float* __restrict__ P) {
    float* p = P + (size_t)blockIdx.x * 4096;
    float v[16];
    float mx = -INFINITY;
    #pragma unroll
    for (int i = 0; i < 16; i++) {
        v[i] = p[threadIdx.x + i * 256];
        mx = fmaxf(mx, v[i]);
    }
    mx = blockReduceMax256(mx);
    float s = 0.f;
    #pragma unroll
    for (int i = 0; i < 16; i++) { v[i] = __expf(v[i] - mx); s += v[i]; }
    s = blockReduceSum256(s);
    const float inv = 1.f / s;
    #pragma unroll
    for (int i = 0; i < 16; i++) p[threadIdx.x + i * 256] = v[i] * inv;
}

__global__ __launch_bounds__(256)
void softmax_fc_kernel(float* __restrict__ P) {
    float* p = P + (size_t)blockIdx.x * 32000;
    float m = -INFINITY, s = 0.f;
    for (int i = threadIdx.x; i < 32000; i += 256) {
        float v = p[i];
        if (v > m) { s = s * __expf(m - v) + 1.f; m = v; }
        else       { s += __expf(v - m); }
    }
    const float M = blockReduceMax256(m);
    s *= __expf(m - M);
    const float S = blockReduceSum256(s);
    const float inv = 1.f / S;
    for (int i = threadIdx.x; i < 32000; i += 256)
        p[i] = __expf(p[i] - M) * inv;
}

// ---------------------------------------------------------------- assemble s
__global__ __launch_bounds__(320)
void assemble_s_kernel(const int* __restrict__ X, const float* __restrict__ Emb,
                       const float* __restrict__ Cf, const float* __restrict__ Mo,
                       __bf16* __restrict__ S) {
    const int m = blockIdx.x;
    const int col = threadIdx.x * 4;
    float4 v;
    if (col < 256)      v = *(const float4*)(Emb + (size_t)X[m] * 256 + col);
    else if (col < 768) v = *(const float4*)(Cf + (size_t)m * 512 + (col - 256));
    else                v = *(const float4*)(Mo + (size_t)m * 512 + (col - 768));
    bf16x4 o;
    o[0] = (__bf16)v.x; o[1] = (__bf16)v.y; o[2] = (__bf16)v.z; o[3] = (__bf16)v.w;
    *(bf16x4*)(S + (size_t)m * 1280 + col) = o;
}

// ---------------------------------------------------------------- launch
extern "C" void kernel_launch(void* const* d_in, const int* in_sizes, int n_in,
                              void* d_out, int out_size, void* d_ws, size_t ws_size,
                              hipStream_t stream) {
    const int*   x    = (const int*)d_in[0];
    const int*   c    = (const int*)d_in[1];
    const float* emb  = (const float*)d_in[2];
    const float* w1 = (const float*)d_in[3],  *b1 = (const float*)d_in[4];
    const float* g1 = (const float*)d_in[5],  *be1 = (const float*)d_in[6];
    const float* w2 = (const float*)d_in[7],  *b2 = (const float*)d_in[8];
    const float* g2 = (const float*)d_in[9],  *be2 = (const float*)d_in[10];
    const float* w3 = (const float*)d_in[11], *b3 = (const float*)d_in[12];
    const float* g3 = (const float*)d_in[13], *be3 = (const float*)d_in[14];
    const float* w4 = (const float*)d_in[15], *b4 = (const float*)d_in[16];
    const float* g4 = (const float*)d_in[17], *be4 = (const float*)d_in[18];
    const float* w5 = (const float*)d_in[19], *b5 = (const float*)d_in[20];
    const float* g5 = (const float*)d_in[21], *be5 = (const float*)d_in[22];
    const float* fcW = (const float*)d_in[23], *fcb = (const float*)d_in[24];
    const float* memK = (const float*)d_in[25], *memV = (const float*)d_in[26];
    float* out = (float*)d_out;

    // -------- workspace --------
    char* W = (char*)d_ws;
    __bf16* fcWT_bf  = (__bf16*)(W + 0);            // 32000x1280 (81,920,000)
    __bf16* memK_bf  = (__bf16*)(W + 81920000);     // 4,194,304
    __bf16* memVT_bf = (__bf16*)(W + 86114304);     // 4,194,304
    __bf16* w5t      = (__bf16*)(W + 90308608);     // 512x3584  (3,670,016)
    __bf16* w4t      = (__bf16*)(W + 93978624);     // 256x1024  (524,288)
    __bf16* w3t      = (__bf16*)(W + 94502912);     // 128x512   (131,072)
    __bf16* w2t      = (__bf16*)(W + 94633984);     // 128x256   (65,536)
    __bf16* w1t      = (__bf16*)(W + 94699520);     // 128x512   (131,072)
    float*  SS       = (float*)(W + 94830592);      // 1024 f
    float*  BB       = (float*)(W + 94834688);      // 512 f
    float2* part     = (float2*)(W + 94836736);     // 131072 f2 (1,048,576)
    __bf16* YA = (__bf16*)(W + 95885312);           // 8,929,280
    __bf16* YB = (__bf16*)(W + 104814592);          // 9,453,568
    char* P = W + 114268160;                        // 34,340,864
    __bf16* Gt      = (__bf16*)P;
    float*  Pc5     = (float*)P;
    float*  scores  = (float*)P;
    __bf16* attn_bf = (__bf16*)(P + 16777216);
    float*  Pmo     = (float*)(P + 25165824);
    float*  cfeat    = (float*)(W + 148609024);
    __bf16* cfeat_bf = (__bf16*)(W + 150706176);
    float*  m_out    = (float*)(W + 151754752);
    __bf16* s_bf     = (__bf16*)(W + 153851904);

    __bf16* Y1 = YA; __bf16* Y3 = YA;
    __bf16* Y2 = YB; __bf16* Y4 = YB;

    // ---------------- weight prep ----------------
    transpose_cast_kernel<<<dim3(1000, 40), 256, 0, stream>>>(fcW, fcWT_bf, 1280, 32000);
    transpose_cast_kernel<<<dim3(16, 128), 256, 0, stream>>>(memV, memVT_bf, 4096, 512);
    cast_bf16_kernel<<<1024, 256, 0, stream>>>(memK, memK_bf, 262144);
    wt_fold_kernel<<<128, 256, 0, stream>>>(w1, b1, nullptr, w1t, BB, 32, 64, 8);
    gather_tr_kernel<<<1024, 256, 0, stream>>>(c, emb, Gt);

    // ---------------- conv1 ----------------
    mfma_gemm_bt<<<dim3(1024, 1), 256, 0, stream>>>(Gt, w1t, BB, Y1 + 64,
        32, 512, 512, 128, 0, 7, 16768LL, 4160, 0LL, 1.0f, 1, 0, 1);
    bn_stats_bf_kernel<32, 127, 130, 512><<<512, 256, 0, stream>>>(Y1, part);
    bn_finalize_kernel<<<32, 64, 0, stream>>>(part, g1, be1, SS, 32, 512,
                                              1.0f / (1024.f * 127.f));
    padfill_kernel<<<1024, 256, 0, stream>>>(Y1, SS, 32, 130,
                                             make_int4(0, 1, 129, 0), 3);
    wt_fold_kernel<<<128, 256, 0, stream>>>(w2, b2, SS, w2t, BB, 64, 32, 8);

    // ---------------- conv2 ----------------
    mfma_gemm_bt<<<dim3(512, 1), 256, 0, stream>>>(Y1, w2t, BB, Y2 + 128,
        64, 256, 256, 64, 4160, 6, 8320LL, 4224, 0LL, 1.0f, 1, 0, 1);
    bn_stats_bf_kernel<64, 62, 66, 256><<<256, 256, 0, stream>>>(Y2, part);
    bn_finalize_kernel<<<64, 64, 0, stream>>>(part, g2, be2, SS, 64, 256,
                                              1.0f / (1024.f * 62.f));
    padfill_kernel<<<1024, 256, 0, stream>>>(Y2, SS, 64, 66,
                                             make_int4(0, 1, 64, 65), 4);
    wt_fold_kernel<<<128, 256, 0, stream>>>(w3, b3, SS, w3t, BB, 128, 64, 8);

    // ---------------- conv3 ----------------
    mfma_gemm_bt<<<dim3(256, 1), 256, 0, stream>>>(Y2, w3t, BB, Y3 + 256,
        128, 512, 512, 128, 4224, 5, 16896LL, 4352, 0LL, 1.0f, 1, 0, 1);
    bn_stats_bf_kernel<128, 30, 34, 256><<<256, 256, 0, stream>>>(Y3, part);
    bn_finalize_kernel<<<128, 64, 0, stream>>>(part, g3, be3, SS, 128, 256,
                                               1.0f / (1024.f * 30.f));
    padfill_kernel<<<1024, 256, 0, stream>>>(Y3, SS, 128, 34,
                                             make_int4(0, 1, 32, 33), 4);
    wt_fold_kernel<<<256, 256, 0, stream>>>(w4, b4, SS, w4t, BB, 256, 128, 8);

    // ---------------- conv4 ----------------
    mfma_gemm_bt<<<dim3(128, 2), 256, 0, stream>>>(Y3, w4t, BB, Y4 + 512,
        256, 1024, 1024, 256, 4352, 4, 34816LL, 4608, 0LL, 1.0f, 1, 0, 1);
    bn_stats_bf_kernel<256, 14, 18, 256><<<256, 256, 0, stream>>>(Y4, part);
    bn_finalize_kernel<<<256, 64, 0, stream>>>(part, g4, be4, SS, 256, 256,
                                               1.0f / (1024.f * 14.f));
    wt_fold_kernel<<<512, 256, 0, stream>>>(w5, b5, SS, w5t, BB, 512, 256, 14);

    // ---------------- conv5 (split-K 8) ----------------
    mfma_gemm_bt<<<dim3(8, 4, 8), 256, 0, stream>>>(Y4 + 512, w5t, nullptr, Pc5,
        512, 3584, 448, 4608, 0, 7, 589824LL, 65536, 524288LL, 1.0f, 0, 0, 0);
    splitk_reduce_kernel<<<512, 256, 0, stream>>>(Pc5, cfeat, BB, 8, 524288, 512, 1);
    bn_stats_cf_kernel<<<256, 256, 0, stream>>>(cfeat, part);
    bn_finalize_kernel<<<512, 64, 0, stream>>>(part, g5, be5, SS, 512, 256,
                                               1.0f / 1024.f);
    bn_apply_both_kernel<<<512, 256, 0, stream>>>(cfeat, cfeat_bf, SS, 131072);

    // ---------------- attention over memory ----------------
    mfma_gemm_bt<<<dim3(8, 32), 256, 0, stream>>>(cfeat_bf, memK_bf, nullptr, scores,
        4096, 512, 512, 512, 0, 7, 65536LL, 524288, 0LL,
        0.04419417382415922f, 0, 1, 0);
    softmax4k_kernel<<<1024, 256, 0, stream>>>(scores);
    cast_bf16_kernel<<<2048, 256, 0, stream>>>(scores, attn_bf, 524288);
    mfma_gemm_bt<<<dim3(8, 4, 4), 256, 0, stream>>>(attn_bf, memVT_bf, nullptr, Pmo,
        512, 4096, 1024, 4096, 0, 7, 524288LL, 65536, 524288LL, 1.0f, 0, 0, 0);
    splitk_reduce_kernel<<<512, 256, 0, stream>>>(Pmo, m_out, nullptr, 4, 524288, 512, 0);

    // ---------------- concat + fc + softmax ----------------
    assemble_s_kernel<<<1024, 320, 0, stream>>>(x, emb, cfeat, m_out, s_bf);
    mfma_gemm256_bt<<<dim3(500), 512, 0, stream>>>(s_bf, fcWT_bf, fcb, out,
                                                   1024, 32000, 1280, 500);
    softmax_fc_kernel<<<1024, 256, 0, stream>>>(out);
}